// Round 10
// baseline (74.781 us; speedup 1.0000x reference)
//
#include <hip/hip_runtime.h>

// Problem constants
#define B_N   2
#define H_LR  64
#define W_LR  64
#define HUP   128
#define WUP   128
#define GRP   4
#define NPT   9
#define EMB   32
#define CGRP  64
#define KIN   256
#define GE    128
#define NOFF  288

typedef __attribute__((ext_vector_type(8))) short short8v;
typedef _Float16 half8v __attribute__((ext_vector_type(8)));
typedef __attribute__((ext_vector_type(4))) float f32x4;

__device__ __forceinline__ ushort f2bf(float f) {
    unsigned u = __float_as_uint(f);
    u += 0x7FFFu + ((u >> 16) & 1u);
    return (ushort)(u >> 16);
}
__device__ __forceinline__ float bf2f(ushort h) {
    return __uint_as_float(((unsigned)h) << 16);
}
__device__ __forceinline__ ushort f2h(float f) {
    _Float16 h = (_Float16)f;
    return __builtin_bit_cast(ushort, h);
}
__device__ __forceinline__ float h2f(ushort u) {
    _Float16 h = __builtin_bit_cast(_Float16, u);
    return (float)h;
}

// ---------------------------------------------------------------------------
// Weight conversion: Wq -> wqbf [128][256]; [Wk;Woff;0] -> wkobf [512][256]
// ---------------------------------------------------------------------------
__global__ __launch_bounds__(256) void convert_w_kernel(
    const float* __restrict__ Wq, const float* __restrict__ Wk,
    const float* __restrict__ Woff, ushort* __restrict__ wqbf,
    ushort* __restrict__ wkobf)
{
    int r = blockIdx.x, k = threadIdx.x;
    if (r < 128) {
        wqbf[r * 256 + k] = f2bf(Wq[r * 256 + k]);
    } else {
        int r2 = r - 128;
        float v = 0.f;
        if (r2 < 128) v = Wk[r2 * 256 + k];
        else if (r2 < 416) v = Woff[(r2 - 128) * 256 + k];
        wkobf[r2 * 256 + k] = f2bf(v);
    }
}

// ---------------------------------------------------------------------------
// Merged bf16 MFMA GEMM for both 1x1 convs, register-prefetch pipelined.
// (unchanged from round 9)
// ---------------------------------------------------------------------------
__global__ __launch_bounds__(256, 4) void mfma_gemm(
    const float* __restrict__ y, const float* __restrict__ x,
    const ushort* __restrict__ WQ, const ushort* __restrict__ WKO,
    const float* __restrict__ bq, const float* __restrict__ bk,
    const float* __restrict__ boff,
    ushort* __restrict__ qbf, ushort* __restrict__ kbf,
    float* __restrict__ offw)
{
    __shared__ __align__(16) ushort sY[64][68];
    __shared__ __align__(16) ushort sB[128][72];

    int bid = blockIdx.x;
    const float* SRC; const ushort* WBF; const float* ba; const float* bb;
    ushort* OBF; float* OFP;
    int M, m0, n0, b;
    if (bid < 512) {
        int mt = bid & 255; b = bid >> 8;
        SRC = y; WBF = WQ; ba = bq; bb = nullptr; OBF = qbf; OFP = nullptr;
        M = 16384; m0 = mt * 64; n0 = 0;
    } else {
        int r = bid - 512;
        int mt = r & 63, nt2 = (r >> 6) & 3; b = r >> 8;
        SRC = x; WBF = WKO; ba = bk; bb = boff; OBF = kbf; OFP = offw;
        M = 4096; m0 = mt * 64; n0 = nt2 * 128;
    }

    int tid = threadIdx.x;
    int lane = tid & 63;
    int wv = tid >> 6, wm = wv >> 1, wn = wv & 1;
    int il = lane & 15, g4 = lane >> 4;
    int st_m4 = tid & 15, st_c = tid >> 4;
    int st_c8 = tid & 7,  st_n = tid >> 3;

    f32x4 acc[2][4];
#pragma unroll
    for (int i = 0; i < 2; ++i)
#pragma unroll
        for (int j = 0; j < 4; ++j) { f32x4 z = {0.f,0.f,0.f,0.f}; acc[i][j] = z; }

    const float* src_b = SRC + (size_t)b * KIN * M;

    float4 ra[4]; short8v rb[4];
#pragma unroll
    for (int i = 0; i < 4; ++i)
        ra[i] = *(const float4*)&src_b[(size_t)(st_c + i * 16) * M + m0 + st_m4 * 4];
#pragma unroll
    for (int i = 0; i < 4; ++i)
        rb[i] = *(const short8v*)&WBF[(size_t)(n0 + st_n + i * 32) * KIN + st_c8 * 8];

    for (int ks = 0; ks < 4; ++ks) {
#pragma unroll
        for (int i = 0; i < 4; ++i) {
            ushort4 h;
            h.x = f2bf(ra[i].x); h.y = f2bf(ra[i].y);
            h.z = f2bf(ra[i].z); h.w = f2bf(ra[i].w);
            *(ushort4*)&sY[st_c + i * 16][st_m4 * 4] = h;
            *(short8v*)&sB[st_n + i * 32][st_c8 * 8] = rb[i];
        }
        __syncthreads();
        if (ks < 3) {
            int k0 = (ks + 1) * 64;
#pragma unroll
            for (int i = 0; i < 4; ++i)
                ra[i] = *(const float4*)&src_b[(size_t)(k0 + st_c + i * 16) * M + m0 + st_m4 * 4];
#pragma unroll
            for (int i = 0; i < 4; ++i)
                rb[i] = *(const short8v*)&WBF[(size_t)(n0 + st_n + i * 32) * KIN + k0 + st_c8 * 8];
        }
#pragma unroll
        for (int kc = 0; kc < 2; ++kc) {
            int kb = kc * 32 + g4 * 8;
            short8v af[2], bfr[4];
#pragma unroll
            for (int mf = 0; mf < 2; ++mf) {
                int m = wm * 32 + mf * 16 + il;
                short8v t;
#pragma unroll
                for (int j = 0; j < 8; ++j) t[j] = (short)sY[kb + j][m];
                af[mf] = t;
            }
#pragma unroll
            for (int nf = 0; nf < 4; ++nf)
                bfr[nf] = *(const short8v*)&sB[wn * 64 + nf * 16 + il][kb];
#pragma unroll
            for (int mf = 0; mf < 2; ++mf)
#pragma unroll
                for (int nf = 0; nf < 4; ++nf)
                    acc[mf][nf] = __builtin_amdgcn_mfma_f32_16x16x32_bf16(
                        af[mf], bfr[nf], acc[mf][nf], 0, 0, 0);
        }
        __syncthreads();
    }

#pragma unroll
    for (int mf = 0; mf < 2; ++mf) {
#pragma unroll
        for (int r = 0; r < 4; ++r) {
            int m = m0 + wm * 32 + mf * 16 + g4 * 4 + r;
            size_t row = (size_t)b * M + m;
#pragma unroll
            for (int nf = 0; nf < 4; ++nf) {
                int n = n0 + wn * 64 + nf * 16 + il;
                float v = acc[mf][nf][r];
                if (n < GE) {
                    OBF[row * 128 + n] = f2bf(v + ba[n]);
                } else {
                    int no = n - GE;
                    if (no < NOFF) OFP[row * 288 + no] = v + bb[no];
                }
            }
        }
    }
}

// ---------------------------------------------------------------------------
// Fused deformable attention — 5-barrier structure.
//   B1 after staging; P0b{S-MFMA+store, geometry}; B2;
//   fused per-px phase (logits+softmax+W) on wave0; B3;
//   O-GEMM; B4; transpose; B5; coalesced stores; [B6+fallback iff needed].
// smem carve (37808 B -> 4 blocks/CU):
//   sXt[64][72] @0 | sS[64][66] @9216 | sGt @17664 | sGz @19968 | sFB @22272
//   sQ[64][40] @22800 | sK[66][40] @27920 | sOff @33200
//   sW[64][72] aliases sK+sOff @27920 ; sOT[64][68] aliases sXt+sS @0
// ---------------------------------------------------------------------------
#define RROWS 6
#define RCOLS 11
#define RPX   66

__global__ __launch_bounds__(256, 4) void deform_kernel(
    const ushort* __restrict__ qbf,  // [B, 16384, 128] bf16 pixel-major
    const ushort* __restrict__ kbf,  // [B, 4096, 128] bf16 pixel-major
    const float* __restrict__ offw,  // [B, 4096, 288] fp32 pixel-major
    const float* __restrict__ x,     // [B, 256, 64, 64] channel-major (input)
    float* __restrict__ out)         // [B, 256, 128, 128]
{
    __shared__ __align__(16) char smem[37808];
    ushort (*sXt)[72] = (ushort(*)[72])(smem);            // x region fp16
    ushort (*sS)[66]  = (ushort(*)[66])(smem + 9216);     // S table fp16
    uint*  sGt        = (uint*)(smem + 17664);            // {ty,tx} fp16 packed
    int*   sGz        = (int*)(smem + 19968);             // zi<<5 | flags
    int*   sFB        = (int*)(smem + 22272);             // count + 64x{item,attn}
    ushort (*sQ)[40]  = (ushort(*)[40])(smem + 22800);    // q bf16
    ushort (*sK)[40]  = (ushort(*)[40])(smem + 27920);    // k region bf16
    float* sOff       = (float*)(smem + 33200);           // offsets fp32
    ushort (*sW)[72]  = (ushort(*)[72])(smem + 27920);    // W fp16 (alias sK+sOff)
    float (*sOT)[68]  = (float(*)[68])(smem);             // out transpose (alias)

    int bx = blockIdx.x;
    int tw = bx & 7, th = (bx >> 3) & 31, g = (bx >> 8) & 3, b = bx >> 10;
    int tid = threadIdx.x;
    int wv_ = tid >> 6, lane = tid & 63;
    int row = lane & 15, kb8 = lane >> 4;

    const int ry0 = th * 2 - 2, rx0 = tw * 8 - 1;

    // ---------------- P0a: staging (coalesced) -----------------------------
    if (tid == 0) sFB[0] = 0;
    if (tid < 192) {                       // zero sXt cols 66..71
        int r = tid / 3, c2 = tid - (tid / 3) * 3;
        *(uint*)&sXt[r][66 + c2 * 2] = 0;
    }
    // x region -> fp16; item = (ch, gy, quad)
    for (int it = tid; it < 1536; it += 256) {
        int quad = it & 3, rest = it >> 2;
        int ch = rest / 6, gy = rest - (rest / 6) * 6;
        int gyg = min(max(ry0 + gy, 0), 63);
        const float* xr = x + ((size_t)b * 256 + g * CGRP + ch) * 4096 + gyg * 64;
        if (tw >= 1 && tw <= 6) {
            float4 f = *(const float4*)&xr[rx0 - 3 + quad * 4];
            const float* fv = (const float*)&f;
#pragma unroll
            for (int j = 0; j < 4; ++j) {
                int col = quad * 4 + j - 3;
                if (col >= 0 && col < RCOLS) sXt[ch][gy * RCOLS + col] = f2h(fv[j]);
            }
        } else {
#pragma unroll
            for (int j = 0; j < 4; ++j) {
                int col = quad * 4 + j - 3;
                if (col >= 0 && col < RCOLS) {
                    int gxg = min(max(rx0 + col, 0), 63);
                    sXt[ch][gy * RCOLS + col] = f2h(xr[gxg]);
                }
            }
        }
    }
    // k region bf16
    for (int i = tid; i < 264; i += 256) {
        int rp = i >> 2, c4 = i & 3;
        int qy = rp / RCOLS, qx = rp - qy * RCOLS;
        int gy = min(max(ry0 + qy, 0), 63), gx = min(max(rx0 + qx, 0), 63);
        *(short8v*)&sK[rp][c4 * 8] =
            *(const short8v*)&kbf[((size_t)b * 4096 + gy * 64 + gx) * 128 +
                                  g * EMB + c4 * 8];
    }
    // q bf16
    {
        int px = tid >> 2, c4 = tid & 3;
        int hup = th * 4 + (px >> 4), wup = tw * 16 + (px & 15);
        *(short8v*)&sQ[px][c4 * 8] =
            *(const short8v*)&qbf[((size_t)b * 16384 + hup * 128 + wup) * 128 +
                                  g * EMB + c4 * 8];
    }
    // offsets (coalesced float4)
    for (int i = tid; i < 288; i += 256) {
        int lr = i / 18, f4 = i - (i / 18) * 18;
        int yy = th * 2 + (lr >> 3), xx = tw * 8 + (lr & 7);
        *(float4*)&sOff[lr * 72 + f4 * 4] =
            *(const float4*)&offw[((size_t)b * 4096 + yy * 64 + xx) * 288 +
                                  g * 72 + f4 * 4];
    }
    __syncthreads();

    // ---------------- P0b: S-GEMM (store直) + geometry ---------------------
    {
        short8v a = *(const short8v*)&sQ[wv_ * 16 + row][kb8 * 8];
#pragma unroll
        for (int nt = 0; nt < 5; ++nt) {
            int rr = nt * 16 + row; if (rr > 65) rr = 65;
            short8v bf = *(const short8v*)&sK[rr][kb8 * 8];
            f32x4 z = {0.f, 0.f, 0.f, 0.f};
            f32x4 d = __builtin_amdgcn_mfma_f32_16x16x32_bf16(a, bf, z, 0, 0, 0);
            int rp = nt * 16 + row;
            if (rp < RPX) {
#pragma unroll
                for (int r = 0; r < 4; ++r)
                    sS[wv_ * 16 + kb8 * 4 + r][rp] = f2h(d[r]);
            }
        }
    }
    for (int item = tid; item < 576; item += 256) {
        int px = item / 9, pt = item - (item / 9) * 9;
        int lx = px & 15, ly = px >> 4;
        int hup = th * 4 + ly, wup = tw * 16 + lx;
        int lr = (ly >> 1) * 8 + (lx >> 1);
        int ij = ((hup & 1) << 1) | (wup & 1);
        float offy = sOff[lr * 72 + pt * 8 + ij];
        float offx = sOff[lr * 72 + pt * 8 + 4 + ij];
        float py  = offy + hup * 0.5f - 0.25f;
        float pxx = offx + wup * 0.5f - 0.25f;
        float y0f = floorf(py), x0f = floorf(pxx);
        float ty = py - y0f, tx = pxx - x0f;
        int y0 = (int)y0f, x0 = (int)x0f;
        int mk = 0;
        if ((unsigned)y0 < 64u && (unsigned)x0 < 64u)         mk |= 1;
        if ((unsigned)y0 < 64u && (unsigned)(x0+1) < 64u)     mk |= 2;
        if ((unsigned)(y0+1) < 64u && (unsigned)x0 < 64u)     mk |= 4;
        if ((unsigned)(y0+1) < 64u && (unsigned)(x0+1) < 64u) mk |= 8;
        int iy = y0 - ry0, ix = x0 - rx0;
        bool inreg = ((unsigned)iy <= (unsigned)(RROWS - 2)) &&
                     ((unsigned)ix <= (unsigned)(RCOLS - 2));
        int fl, zp;
        if (!mk)        { fl = 16; zp = 0; }
        else if (inreg) { fl = mk | 16; zp = iy * RCOLS + ix; }
        else            { fl = mk; zp = (y0 + 1) * 66 + (x0 + 1); }
        sGt[item] = (uint)f2h(ty) | ((uint)f2h(tx) << 16);
        sGz[item] = (zp << 5) | fl;
    }
    __syncthreads();

    // ---------------- P1': fused logits + softmax + W-build (wave 0) -------
    if (tid < 64) {
        int px = tid;
        float aa[NPT], ty9[NPT], tx9[NPT];
        int gz9[NPT];
#pragma unroll
        for (int p = 0; p < NPT; ++p) {
            int item = px * 9 + p;
            uint gt = sGt[item];
            ty9[p] = h2f((ushort)gt); tx9[p] = h2f((ushort)(gt >> 16));
            gz9[p] = sGz[item];
        }
#pragma unroll
        for (int p = 0; p < NPT; ++p) {
            int z = gz9[p];
            int fl = z & 31;
            float ty = ty9[p], tx = tx9[p];
            float a;
            if (fl & 16) {
                int zi = z >> 5;
                float w00 = (1.f - ty) * (1.f - tx), w01 = (1.f - ty) * tx;
                float w10 = ty * (1.f - tx), w11 = ty * tx;
                a  = (fl & 1) ? w00 * h2f(sS[px][zi])             : 0.f;
                a += (fl & 2) ? w01 * h2f(sS[px][zi + 1])         : 0.f;
                a += (fl & 4) ? w10 * h2f(sS[px][zi + RCOLS])     : 0.f;
                a += (fl & 8) ? w11 * h2f(sS[px][zi + RCOLS + 1]) : 0.f;
            } else {
                int t = z >> 5;
                int y0 = t / 66 - 1, x0 = t - (t / 66) * 66 - 1;
                a = 0.f;
#pragma unroll
                for (int c = 0; c < 4; ++c) if ((fl >> c) & 1) {
                    int dy = c >> 1, dx = c & 1;
                    float wgt = (dy ? ty : 1.f - ty) * (dx ? tx : 1.f - tx);
                    const ushort* kr = &kbf[((size_t)b * 4096 + (y0 + dy) * 64 + x0 + dx) * 128 +
                                            g * EMB];
                    float dot = 0.f;
                    for (int e = 0; e < EMB; ++e) dot += bf2f(sQ[px][e]) * bf2f(kr[e]);
                    a += wgt * dot;
                }
            }
            aa[p] = a;
        }
        // softmax in registers
        float mx = aa[0];
#pragma unroll
        for (int p = 1; p < NPT; ++p) mx = fmaxf(mx, aa[p]);
        float s = 0.f;
#pragma unroll
        for (int p = 0; p < NPT; ++p) { aa[p] = __expf(aa[p] - mx); s += aa[p]; }
        float inv = 1.f / s;
        // zero own W row (144 B = 9 x float4)
        {
            float4 z4 = make_float4(0.f, 0.f, 0.f, 0.f);
            char* wr = (char*)&sW[px][0];
#pragma unroll
            for (int j = 0; j < 9; ++j) *(float4*)(wr + j * 16) = z4;
        }
        // build W row / record fallbacks
#pragma unroll
        for (int p = 0; p < NPT; ++p) {
            float a = aa[p] * inv;
            int z = gz9[p];
            int fl = z & 31;
            if (fl & 16) {
                float ty = ty9[p], tx = tx9[p];
                int zi = z >> 5;
                ushort* c = &sW[px][zi];
                if (fl & 1) c[0]         = f2h(h2f(c[0])         + (1.f-ty)*(1.f-tx)*a);
                if (fl & 2) c[1]         = f2h(h2f(c[1])         + (1.f-ty)*tx*a);
                if (fl & 4) c[RCOLS]     = f2h(h2f(c[RCOLS])     + ty*(1.f-tx)*a);
                if (fl & 8) c[RCOLS + 1] = f2h(h2f(c[RCOLS + 1]) + ty*tx*a);
            } else {
                int old = atomicAdd(&sFB[0], 1);
                if (old < 64) {
                    sFB[1 + 2 * old] = px * 9 + p;
                    sFB[2 + 2 * old] = __float_as_int(a);
                }
            }
        }
    }
    __syncthreads();

    // ---------------- P5: O-GEMM (f16 MFMA) --------------------------------
    f32x4 oacc[4];
    {
        half8v bfm0[4], bfm1[4], bfm2[4];
#pragma unroll
        for (int nt = 0; nt < 4; ++nt) {
            bfm0[nt] = *(const half8v*)&sXt[nt * 16 + row][kb8 * 8];
            bfm1[nt] = *(const half8v*)&sXt[nt * 16 + row][32 + kb8 * 8];
            bfm2[nt] = *(const half8v*)&sXt[nt * 16 + row][64];
        }
        int px = wv_ * 16 + row;
        half8v af0 = *(const half8v*)&sW[px][kb8 * 8];
        half8v af1 = *(const half8v*)&sW[px][32 + kb8 * 8];
        half8v af2 = {0,0,0,0,0,0,0,0};
        if (kb8 == 0) af2 = *(const half8v*)&sW[px][64];   // cols 66..71 zeroed

#pragma unroll
        for (int nt = 0; nt < 4; ++nt) { f32x4 z = {0.f,0.f,0.f,0.f}; oacc[nt] = z; }
#pragma unroll
        for (int nt = 0; nt < 4; ++nt) {
            oacc[nt] = __builtin_amdgcn_mfma_f32_16x16x32_f16(af0, bfm0[nt], oacc[nt], 0, 0, 0);
            oacc[nt] = __builtin_amdgcn_mfma_f32_16x16x32_f16(af1, bfm1[nt], oacc[nt], 0, 0, 0);
            oacc[nt] = __builtin_amdgcn_mfma_f32_16x16x32_f16(af2, bfm2[nt], oacc[nt], 0, 0, 0);
        }
    }
    __syncthreads();           // sXt/sS/sW reads done; safe to alias sOT

    // transpose to sOT[ch][hupl*16 + wupl]
#pragma unroll
    for (int nt = 0; nt < 4; ++nt)
        *(f32x4*)&sOT[nt * 16 + row][wv_ * 16 + kb8 * 4] = oacc[nt];
    __syncthreads();

    // coalesced float4 stores
#pragma unroll
    for (int i = 0; i < 4; ++i) {
        int pr = i * 64 + (tid >> 2);
        int ch = pr >> 2, hupl = pr & 3, q = tid & 3;
        float4 v = *(float4*)&sOT[ch][hupl * 16 + q * 4];
        *(float4*)(out + ((size_t)b * 256 + g * CGRP + ch) * 16384 +
                   (size_t)(th * 4 + hupl) * 128 + tw * 16 + q * 4) = v;
    }

    // ---------------- P6: rare out-of-region fallback ----------------------
    int nfb = min(sFB[0], 64);
    if (nfb > 0) {
        __syncthreads();
        for (int i = 0; i < nfb; ++i) {
            if (tid < 64) {
                int item = sFB[1 + 2 * i];
                float a  = __int_as_float(sFB[2 + 2 * i]);
                int px = item / 9;
                uint gt = sGt[item];
                float ty = h2f((ushort)gt), tx = h2f((ushort)(gt >> 16));
                int z = sGz[item];
                int fl = z & 15;
                int t = z >> 5;
                int y0 = t / 66 - 1, x0 = t - (t / 66) * 66 - 1;
                const float* xg = x + ((size_t)b * 256 + g * CGRP + tid) * 4096;
                float v = 0.f;
                if (fl & 1) v += (1.f-ty)*(1.f-tx)*a * xg[y0*64 + x0];
                if (fl & 2) v += (1.f-ty)*tx*a       * xg[y0*64 + x0 + 1];
                if (fl & 4) v += ty*(1.f-tx)*a       * xg[(y0+1)*64 + x0];
                if (fl & 8) v += ty*tx*a             * xg[(y0+1)*64 + x0 + 1];
                int hup = th * 4 + (px >> 4), wup = tw * 16 + (px & 15);
                float* op = out + ((size_t)b * 256 + g * CGRP + tid) * 16384 +
                            hup * 128 + wup;
                *op += v;
            }
        }
    }
}

// ---------------------------------------------------------------------------
extern "C" void kernel_launch(void* const* d_in, const int* in_sizes, int n_in,
                              void* d_out, int out_size, void* d_ws, size_t ws_size,
                              hipStream_t stream)
{
    const float* y    = (const float*)d_in[0];
    const float* x    = (const float*)d_in[1];
    const float* Wq   = (const float*)d_in[2];
    const float* bq   = (const float*)d_in[3];
    const float* Wk   = (const float*)d_in[4];
    const float* bk   = (const float*)d_in[5];
    const float* Woff = (const float*)d_in[6];
    const float* boff = (const float*)d_in[7];
    float* out = (float*)d_out;

    // workspace layout (20.3 MB total)
    ushort* wqbf  = (ushort*)d_ws;                            // 128*256
    ushort* wkobf = wqbf + 128 * 256;                         // 512*256
    ushort* qbf   = wkobf + 512 * 256;                        // 2*16384*128
    ushort* kbf   = qbf + (size_t)B_N * 16384 * 128;          // 2*4096*128
    float*  offw  = (float*)(kbf + (size_t)B_N * 4096 * 128); // 2*4096*288

    // weights -> bf16 (zero-padded koff rows 416..511)
    convert_w_kernel<<<dim3(640), dim3(256), 0, stream>>>(Wq, Wk, Woff, wqbf, wkobf);

    // both convs in one pipelined launch
    mfma_gemm<<<dim3(1024), dim3(256), 0, stream>>>(
        y, x, wqbf, wkobf, bq, bk, boff, qbf, kbf, offw);

    // fused deformable attention
    deform_kernel<<<dim3(2048), dim3(256), 0, stream>>>(qbf, kbf, offw, x, out);
}

// Round 11
// 64.864 us; speedup vs baseline: 1.1529x; 1.1529x over previous
//
#include <hip/hip_runtime.h>

// Problem constants
#define B_N   2
#define H_LR  64
#define W_LR  64
#define HUP   128
#define WUP   128
#define GRP   4
#define NPT   9
#define EMB   32
#define CGRP  64
#define KIN   256
#define GE    128
#define NOFF  288

typedef __attribute__((ext_vector_type(8))) short short8v;
typedef _Float16 half8v __attribute__((ext_vector_type(8)));
typedef __attribute__((ext_vector_type(4))) float f32x4;

__device__ __forceinline__ ushort f2bf(float f) {
    unsigned u = __float_as_uint(f);
    u += 0x7FFFu + ((u >> 16) & 1u);
    return (ushort)(u >> 16);
}
__device__ __forceinline__ float bf2f(ushort h) {
    return __uint_as_float(((unsigned)h) << 16);
}
__device__ __forceinline__ ushort f2h(float f) {
    _Float16 h = (_Float16)f;
    return __builtin_bit_cast(ushort, h);
}
__device__ __forceinline__ float h2f(ushort u) {
    _Float16 h = __builtin_bit_cast(_Float16, u);
    return (float)h;
}

// ---------------------------------------------------------------------------
// Weight conversion: Wq -> wqbf [128][256]; [Wk;Woff;0] -> wkobf [512][256]
// ---------------------------------------------------------------------------
__global__ __launch_bounds__(256) void convert_w_kernel(
    const float* __restrict__ Wq, const float* __restrict__ Wk,
    const float* __restrict__ Woff, ushort* __restrict__ wqbf,
    ushort* __restrict__ wkobf)
{
    int r = blockIdx.x, k = threadIdx.x;
    if (r < 128) {
        wqbf[r * 256 + k] = f2bf(Wq[r * 256 + k]);
    } else {
        int r2 = r - 128;
        float v = 0.f;
        if (r2 < 128) v = Wk[r2 * 256 + k];
        else if (r2 < 416) v = Woff[(r2 - 128) * 256 + k];
        wkobf[r2 * 256 + k] = f2bf(v);
    }
}

// ---------------------------------------------------------------------------
// Merged bf16 MFMA GEMM for both 1x1 convs, register-prefetch pipelined.
// blocks [0,512):   q  = Wq@y+bq    M=16384, BM=64, BN=128 (1 ntile)
// blocks [512,1024): koff = [Wk;Woff]@x+b  M=4096, BM=64, 4 ntiles of 128
// ---------------------------------------------------------------------------
__global__ __launch_bounds__(256, 4) void mfma_gemm(
    const float* __restrict__ y, const float* __restrict__ x,
    const ushort* __restrict__ WQ, const ushort* __restrict__ WKO,
    const float* __restrict__ bq, const float* __restrict__ bk,
    const float* __restrict__ boff,
    ushort* __restrict__ qbf, ushort* __restrict__ kbf,
    float* __restrict__ offw)
{
    __shared__ __align__(16) ushort sY[64][68];
    __shared__ __align__(16) ushort sB[128][72];

    int bid = blockIdx.x;
    const float* SRC; const ushort* WBF; const float* ba; const float* bb;
    ushort* OBF; float* OFP;
    int M, m0, n0, b;
    if (bid < 512) {
        int mt = bid & 255; b = bid >> 8;
        SRC = y; WBF = WQ; ba = bq; bb = nullptr; OBF = qbf; OFP = nullptr;
        M = 16384; m0 = mt * 64; n0 = 0;
    } else {
        int r = bid - 512;
        int mt = r & 63, nt2 = (r >> 6) & 3; b = r >> 8;
        SRC = x; WBF = WKO; ba = bk; bb = boff; OBF = kbf; OFP = offw;
        M = 4096; m0 = mt * 64; n0 = nt2 * 128;
    }

    int tid = threadIdx.x;
    int lane = tid & 63;
    int wv = tid >> 6, wm = wv >> 1, wn = wv & 1;
    int il = lane & 15, g4 = lane >> 4;
    int st_m4 = tid & 15, st_c = tid >> 4;
    int st_c8 = tid & 7,  st_n = tid >> 3;

    f32x4 acc[2][4];
#pragma unroll
    for (int i = 0; i < 2; ++i)
#pragma unroll
        for (int j = 0; j < 4; ++j) { f32x4 z = {0.f,0.f,0.f,0.f}; acc[i][j] = z; }

    const float* src_b = SRC + (size_t)b * KIN * M;

    float4 ra[4]; short8v rb[4];
#pragma unroll
    for (int i = 0; i < 4; ++i)
        ra[i] = *(const float4*)&src_b[(size_t)(st_c + i * 16) * M + m0 + st_m4 * 4];
#pragma unroll
    for (int i = 0; i < 4; ++i)
        rb[i] = *(const short8v*)&WBF[(size_t)(n0 + st_n + i * 32) * KIN + st_c8 * 8];

    for (int ks = 0; ks < 4; ++ks) {
#pragma unroll
        for (int i = 0; i < 4; ++i) {
            ushort4 h;
            h.x = f2bf(ra[i].x); h.y = f2bf(ra[i].y);
            h.z = f2bf(ra[i].z); h.w = f2bf(ra[i].w);
            *(ushort4*)&sY[st_c + i * 16][st_m4 * 4] = h;
            *(short8v*)&sB[st_n + i * 32][st_c8 * 8] = rb[i];
        }
        __syncthreads();
        if (ks < 3) {
            int k0 = (ks + 1) * 64;
#pragma unroll
            for (int i = 0; i < 4; ++i)
                ra[i] = *(const float4*)&src_b[(size_t)(k0 + st_c + i * 16) * M + m0 + st_m4 * 4];
#pragma unroll
            for (int i = 0; i < 4; ++i)
                rb[i] = *(const short8v*)&WBF[(size_t)(n0 + st_n + i * 32) * KIN + k0 + st_c8 * 8];
        }
#pragma unroll
        for (int kc = 0; kc < 2; ++kc) {
            int kb = kc * 32 + g4 * 8;
            short8v af[2], bfr[4];
#pragma unroll
            for (int mf = 0; mf < 2; ++mf) {
                int m = wm * 32 + mf * 16 + il;
                short8v t;
#pragma unroll
                for (int j = 0; j < 8; ++j) t[j] = (short)sY[kb + j][m];
                af[mf] = t;
            }
#pragma unroll
            for (int nf = 0; nf < 4; ++nf)
                bfr[nf] = *(const short8v*)&sB[wn * 64 + nf * 16 + il][kb];
#pragma unroll
            for (int mf = 0; mf < 2; ++mf)
#pragma unroll
                for (int nf = 0; nf < 4; ++nf)
                    acc[mf][nf] = __builtin_amdgcn_mfma_f32_16x16x32_bf16(
                        af[mf], bfr[nf], acc[mf][nf], 0, 0, 0);
        }
        __syncthreads();
    }

#pragma unroll
    for (int mf = 0; mf < 2; ++mf) {
#pragma unroll
        for (int r = 0; r < 4; ++r) {
            int m = m0 + wm * 32 + mf * 16 + g4 * 4 + r;
            size_t row = (size_t)b * M + m;
#pragma unroll
            for (int nf = 0; nf < 4; ++nf) {
                int n = n0 + wn * 64 + nf * 16 + il;
                float v = acc[mf][nf][r];
                if (n < GE) {
                    OBF[row * 128 + n] = f2bf(v + ba[n]);
                } else {
                    int no = n - GE;
                    if (no < NOFF) OFP[row * 288 + no] = v + bb[no];
                }
            }
        }
    }
}

// ---------------------------------------------------------------------------
// Fused deformable attention via per-block dense MFMA GEMMs.
// (round-7 proposal version — best measured at 41.5 µs)
// ---------------------------------------------------------------------------
#define RROWS 6
#define RCOLS 11
#define RPX   66

__global__ __launch_bounds__(256, 4) void deform_kernel(
    const ushort* __restrict__ qbf,  // [B, 16384, 128] bf16 pixel-major
    const ushort* __restrict__ kbf,  // [B, 4096, 128] bf16 pixel-major
    const float* __restrict__ offw,  // [B, 4096, 288] fp32 pixel-major
    const float* __restrict__ x,     // [B, 256, 64, 64] channel-major (input)
    float* __restrict__ out)         // [B, 256, 128, 128]
{
    __shared__ __align__(16) ushort sXt[64][96];  // x region fp16 [ch][rp], 66..95 zero
    __shared__ __align__(16) ushort sK[66][40];   // k region bf16
    __shared__ __align__(16) ushort sQ[64][40];   // q bf16
    __shared__ __align__(16) ushort sSW[64][72];  // P0: sOff fp32; P1+: S then W fp16
    __shared__ uint   sGt[576];                   // packed {ty,tx} fp16
    __shared__ int    sGz[576];                   // packed zi + flags
    __shared__ float  sAttn[576];                 // logits -> normalized attn
    __shared__ int    sFB[129];                   // fallback list

    int bx = blockIdx.x;
    int tw = bx & 7, th = (bx >> 3) & 31, g = (bx >> 8) & 3, b = bx >> 10;
    int tid = threadIdx.x;
    int wv_ = tid >> 6, lane = tid & 63;
    int row = lane & 15, kb8 = lane >> 4;

    const int ry0 = th * 2 - 2, rx0 = tw * 8 - 1;
    float* sOff = (float*)&sSW[0][0];             // [16][72] fp32 alias

    // ---------------- P0a: all staging (coalesced) -------------------------
    if (tid == 0) sFB[0] = 0;
    // zero sXt pad cols 66..95
    for (int i = tid; i < 960; i += 256) {
        int r = i / 15, j = i - (i / 15) * 15;
        *(uint*)&sXt[r][66 + j * 2] = 0;
    }
    // x region -> fp16 (gy-major lane map; interior tiles use float4 loads)
    for (int s = tid; s < 384; s += 256) {
        int gy = s % 6, ch = s / 6;
        int gyg = min(max(ry0 + gy, 0), 63);
        const float* xr = x + ((size_t)b * 256 + g * CGRP + ch) * 4096 + gyg * 64;
        ushort* dst = &sXt[ch][gy * RCOLS];
        if (tw >= 1 && tw <= 6) {
            int a0 = rx0 - 3;                    // 16B-aligned, in-bounds
            float v[16];
#pragma unroll
            for (int t4 = 0; t4 < 4; ++t4) {
                float4 f = *(const float4*)&xr[a0 + t4 * 4];
                v[t4*4+0] = f.x; v[t4*4+1] = f.y; v[t4*4+2] = f.z; v[t4*4+3] = f.w;
            }
#pragma unroll
            for (int qx = 0; qx < RCOLS; ++qx) dst[qx] = f2h(v[qx + 3]);
        } else {
#pragma unroll
            for (int qx = 0; qx < RCOLS; ++qx) {
                int gxg = min(max(rx0 + qx, 0), 63);
                dst[qx] = f2h(xr[gxg]);
            }
        }
    }
    // k region bf16
    for (int i = tid; i < 264; i += 256) {
        int rp = i >> 2, c4 = i & 3;
        int qy = rp / RCOLS, qx = rp - qy * RCOLS;
        int gy = min(max(ry0 + qy, 0), 63), gx = min(max(rx0 + qx, 0), 63);
        *(short8v*)&sK[rp][c4 * 8] =
            *(const short8v*)&kbf[((size_t)b * 4096 + gy * 64 + gx) * 128 +
                                  g * EMB + c4 * 8];
    }
    // q bf16
    {
        int px = tid >> 2, c4 = tid & 3;
        int hup = th * 4 + (px >> 4), wup = tw * 16 + (px & 15);
        *(short8v*)&sQ[px][c4 * 8] =
            *(const short8v*)&qbf[((size_t)b * 16384 + hup * 128 + wup) * 128 +
                                  g * EMB + c4 * 8];
    }
    // offsets (coalesced float4) -> sOff
    for (int i = tid; i < 288; i += 256) {
        int lr = i / 18, f4 = i - (i / 18) * 18;
        int yy = th * 2 + (lr >> 3), xx = tw * 8 + (lr & 7);
        *(float4*)&sOff[lr * 72 + f4 * 4] =
            *(const float4*)&offw[((size_t)b * 4096 + yy * 64 + xx) * 288 +
                                  g * 72 + f4 * 4];
    }
    __syncthreads();

    // ---------------- P0b: S-GEMM (to regs) + geometry ---------------------
    f32x4 sreg[5];
    {
        short8v a = *(const short8v*)&sQ[wv_ * 16 + row][kb8 * 8];
#pragma unroll
        for (int nt = 0; nt < 5; ++nt) {
            int rr = nt * 16 + row; if (rr > 65) rr = 65;   // tail clamp
            short8v bf = *(const short8v*)&sK[rr][kb8 * 8];
            f32x4 z = {0.f, 0.f, 0.f, 0.f};
            sreg[nt] = __builtin_amdgcn_mfma_f32_16x16x32_bf16(a, bf, z, 0, 0, 0);
        }
    }
    for (int item = tid; item < 576; item += 256) {
        int px = item / 9, pt = item - (item / 9) * 9;
        int lx = px & 15, ly = px >> 4;
        int hup = th * 4 + ly, wup = tw * 16 + lx;
        int lr = (ly >> 1) * 8 + (lx >> 1);
        int ij = ((hup & 1) << 1) | (wup & 1);
        float offy = sOff[lr * 72 + pt * 8 + ij];
        float offx = sOff[lr * 72 + pt * 8 + 4 + ij];
        float py  = offy + hup * 0.5f - 0.25f;
        float pxx = offx + wup * 0.5f - 0.25f;
        float y0f = floorf(py), x0f = floorf(pxx);
        float ty = py - y0f, tx = pxx - x0f;
        int y0 = (int)y0f, x0 = (int)x0f;
        int mk = 0;
        if ((unsigned)y0 < 64u && (unsigned)x0 < 64u)         mk |= 1;
        if ((unsigned)y0 < 64u && (unsigned)(x0+1) < 64u)     mk |= 2;
        if ((unsigned)(y0+1) < 64u && (unsigned)x0 < 64u)     mk |= 4;
        if ((unsigned)(y0+1) < 64u && (unsigned)(x0+1) < 64u) mk |= 8;
        int iy = y0 - ry0, ix = x0 - rx0;
        bool inreg = ((unsigned)iy <= (unsigned)(RROWS - 2)) &&
                     ((unsigned)ix <= (unsigned)(RCOLS - 2));
        int fl, zp;
        if (!mk)        { fl = 16; zp = 0; }
        else if (inreg) { fl = mk | 16; zp = iy * RCOLS + ix; }
        else            { fl = mk; zp = (y0 + 1) * 66 + (x0 + 1); }
        sGt[item] = (uint)f2h(ty) | ((uint)f2h(tx) << 16);
        sGz[item] = (zp << 5) | fl;
    }
    __syncthreads();

    // ---------------- P1: store S as fp16 (overwrites sOff) ----------------
#pragma unroll
    for (int nt = 0; nt < 5; ++nt) {
        int rp = nt * 16 + row;
        if (rp < RPX) {
#pragma unroll
            for (int r = 0; r < 4; ++r)
                sSW[wv_ * 16 + kb8 * 4 + r][rp] = f2h(sreg[nt][r]);
        }
    }
    __syncthreads();

    // ---------------- P2: attention logits ---------------------------------
    for (int item = tid; item < 576; item += 256) {
        int px = item / 9;
        uint gt = sGt[item];
        float ty = h2f((ushort)gt), tx = h2f((ushort)(gt >> 16));
        int z = sGz[item];
        int fl = z & 31;
        float a;
        if (fl & 16) {
            int zi = z >> 5;
            float w00 = (1.f - ty) * (1.f - tx), w01 = (1.f - ty) * tx;
            float w10 = ty * (1.f - tx), w11 = ty * tx;
            a  = (fl & 1) ? w00 * h2f(sSW[px][zi])             : 0.f;
            a += (fl & 2) ? w01 * h2f(sSW[px][zi + 1])         : 0.f;
            a += (fl & 4) ? w10 * h2f(sSW[px][zi + RCOLS])     : 0.f;
            a += (fl & 8) ? w11 * h2f(sSW[px][zi + RCOLS + 1]) : 0.f;
        } else {
            int t = z >> 5;
            int y0 = t / 66 - 1, x0 = t - (t / 66) * 66 - 1;
            a = 0.f;
#pragma unroll
            for (int c = 0; c < 4; ++c) if ((fl >> c) & 1) {
                int dy = c >> 1, dx = c & 1;
                float wgt = (dy ? ty : 1.f - ty) * (dx ? tx : 1.f - tx);
                const ushort* kr = &kbf[((size_t)b * 4096 + (y0 + dy) * 64 + x0 + dx) * 128 +
                                        g * EMB];
                float dot = 0.f;
                for (int e = 0; e < EMB; ++e) dot += bf2f(sQ[px][e]) * bf2f(kr[e]);
                a += wgt * dot;
            }
            int old = atomicAdd(&sFB[0], 1);
            if (old < 128) sFB[1 + old] = item;
        }
        sAttn[item] = a;
    }
    __syncthreads();

    // ---------------- P3: softmax (tid<64)  |  zero W (tid>=64) ------------
    if (tid < 64) {
        float aa[NPT];
        float mx = -1e30f;
#pragma unroll
        for (int p = 0; p < NPT; ++p) { aa[p] = sAttn[tid * 9 + p]; mx = fmaxf(mx, aa[p]); }
        float s = 0.f;
#pragma unroll
        for (int p = 0; p < NPT; ++p) { aa[p] = __expf(aa[p] - mx); s += aa[p]; }
        float inv = 1.f / s;
#pragma unroll
        for (int p = 0; p < NPT; ++p) sAttn[tid * 9 + p] = aa[p] * inv;
    } else {
        float4* p = (float4*)&sSW[0][0];
        float4 z4 = make_float4(0.f, 0.f, 0.f, 0.f);
        for (int i = tid - 64; i < 576; i += 192) p[i] = z4;
    }
    __syncthreads();

    // ---------------- P4: W-build (tid<64, serial fp16 RMW) ----------------
    if (tid < 64) {
        int px = tid;
#pragma unroll
        for (int pt = 0; pt < NPT; ++pt) {
            int item = px * 9 + pt;
            int z = sGz[item];
            int fl = z & 31;
            if (!(fl & 16)) continue;
            uint gt = sGt[item];
            float ty = h2f((ushort)gt), tx = h2f((ushort)(gt >> 16));
            float a = sAttn[item];
            int zi = z >> 5;
            ushort* c = &sSW[px][zi];
            if (fl & 1) c[0]         = f2h(h2f(c[0])         + (1.f-ty)*(1.f-tx)*a);
            if (fl & 2) c[1]         = f2h(h2f(c[1])         + (1.f-ty)*tx*a);
            if (fl & 4) c[RCOLS]     = f2h(h2f(c[RCOLS])     + ty*(1.f-tx)*a);
            if (fl & 8) c[RCOLS + 1] = f2h(h2f(c[RCOLS + 1]) + ty*tx*a);
        }
    }
    __syncthreads();

    // ---------------- P5: O-GEMM (f16 MFMA) + store -------------------------
    {
        half8v bfm[3][4];
#pragma unroll
        for (int kt = 0; kt < 3; ++kt)
#pragma unroll
            for (int nt = 0; nt < 4; ++nt)
                bfm[kt][nt] = *(const half8v*)&sXt[nt * 16 + row][kt * 32 + kb8 * 8];

        int px = wv_ * 16 + row;
        half8v af0 = *(const half8v*)&sSW[px][kb8 * 8];
        half8v af1 = *(const half8v*)&sSW[px][32 + kb8 * 8];
        half8v af2 = {0,0,0,0,0,0,0,0};
        if (kb8 == 0) af2 = *(const half8v*)&sSW[px][64];   // cols 66..71 zeroed

        f32x4 acc[4];
#pragma unroll
        for (int nt = 0; nt < 4; ++nt) { f32x4 z = {0.f,0.f,0.f,0.f}; acc[nt] = z; }
#pragma unroll
        for (int nt = 0; nt < 4; ++nt) {
            acc[nt] = __builtin_amdgcn_mfma_f32_16x16x32_f16(af0, bfm[0][nt], acc[nt], 0, 0, 0);
            acc[nt] = __builtin_amdgcn_mfma_f32_16x16x32_f16(af1, bfm[1][nt], acc[nt], 0, 0, 0);
            acc[nt] = __builtin_amdgcn_mfma_f32_16x16x32_f16(af2, bfm[2][nt], acc[nt], 0, 0, 0);
        }
        int hup = th * 4 + wv_;
#pragma unroll
        for (int nt = 0; nt < 4; ++nt) {
            int ch = nt * 16 + row;
            float* ob = out + ((size_t)b * 256 + g * CGRP + ch) * 16384 +
                        hup * 128 + tw * 16 + kb8 * 4;
#pragma unroll
            for (int r = 0; r < 4; ++r) ob[r] = acc[nt][r];
        }
    }
    __syncthreads();

    // ---------------- P6: rare out-of-region fallback -----------------------
    int nfb = min(sFB[0], 128);
    for (int i = 0; i < nfb; ++i) {
        if (tid < 64) {
            int item = sFB[1 + i];
            int px = item / 9;
            uint gt = sGt[item];
            float ty = h2f((ushort)gt), tx = h2f((ushort)(gt >> 16));
            int z = sGz[item];
            float a = sAttn[item];
            int fl = z & 15;
            int t = z >> 5;
            int y0 = t / 66 - 1, x0 = t - (t / 66) * 66 - 1;
            const float* xg = x + ((size_t)b * 256 + g * CGRP + tid) * 4096;
            float v = 0.f;
            if (fl & 1) v += (1.f-ty)*(1.f-tx)*a * xg[y0*64 + x0];
            if (fl & 2) v += (1.f-ty)*tx*a       * xg[y0*64 + x0 + 1];
            if (fl & 4) v += ty*(1.f-tx)*a       * xg[(y0+1)*64 + x0];
            if (fl & 8) v += ty*tx*a             * xg[(y0+1)*64 + x0 + 1];
            int hup = th * 4 + (px >> 4), wup = tw * 16 + (px & 15);
            float* op = out + ((size_t)b * 256 + g * CGRP + tid) * 16384 +
                        hup * 128 + wup;
            *op += v;
        }
    }
}

// ---------------------------------------------------------------------------
extern "C" void kernel_launch(void* const* d_in, const int* in_sizes, int n_in,
                              void* d_out, int out_size, void* d_ws, size_t ws_size,
                              hipStream_t stream)
{
    const float* y    = (const float*)d_in[0];
    const float* x    = (const float*)d_in[1];
    const float* Wq   = (const float*)d_in[2];
    const float* bq   = (const float*)d_in[3];
    const float* Wk   = (const float*)d_in[4];
    const float* bk   = (const float*)d_in[5];
    const float* Woff = (const float*)d_in[6];
    const float* boff = (const float*)d_in[7];
    float* out = (float*)d_out;

    // workspace layout (20.3 MB total)
    ushort* wqbf  = (ushort*)d_ws;                            // 128*256
    ushort* wkobf = wqbf + 128 * 256;                         // 512*256
    ushort* qbf   = wkobf + 512 * 256;                        // 2*16384*128
    ushort* kbf   = qbf + (size_t)B_N * 16384 * 128;          // 2*4096*128
    float*  offw  = (float*)(kbf + (size_t)B_N * 4096 * 128); // 2*4096*288

    // weights -> bf16 (zero-padded koff rows 416..511)
    convert_w_kernel<<<dim3(640), dim3(256), 0, stream>>>(Wq, Wk, Woff, wqbf, wkobf);

    // both convs in one pipelined launch
    mfma_gemm<<<dim3(1024), dim3(256), 0, stream>>>(
        y, x, wqbf, wkobf, bq, bk, boff, qbf, kbf, offw);

    // fused deformable attention
    deform_kernel<<<dim3(2048), dim3(256), 0, stream>>>(qbf, kbf, offw, x, out);
}

// Round 12
// 63.994 us; speedup vs baseline: 1.1686x; 1.0136x over previous
//
#include <hip/hip_runtime.h>

// Problem constants
#define B_N   2
#define H_LR  64
#define W_LR  64
#define HUP   128
#define WUP   128
#define GRP   4
#define NPT   9
#define EMB   32
#define CGRP  64
#define KIN   256
#define GE    128
#define NOFF  288

typedef __attribute__((ext_vector_type(8))) short short8v;
typedef _Float16 half8v __attribute__((ext_vector_type(8)));
typedef __attribute__((ext_vector_type(4))) float f32x4;

__device__ __forceinline__ ushort f2bf(float f) {
    unsigned u = __float_as_uint(f);
    u += 0x7FFFu + ((u >> 16) & 1u);
    return (ushort)(u >> 16);
}
__device__ __forceinline__ float bf2f(ushort h) {
    return __uint_as_float(((unsigned)h) << 16);
}
__device__ __forceinline__ ushort f2h(float f) {
    _Float16 h = (_Float16)f;
    return __builtin_bit_cast(ushort, h);
}
__device__ __forceinline__ float h2f(ushort u) {
    _Float16 h = __builtin_bit_cast(_Float16, u);
    return (float)h;
}

// ---------------------------------------------------------------------------
// Merged bf16 MFMA GEMM for both 1x1 convs, register-prefetch pipelined.
// Weights converted fp32 -> bf16 at prefetch time (no separate convert pass).
// blocks [0,512):   q  = Wq@y+bq    M=16384, BM=64, BN=128 (1 ntile)
// blocks [512,1024): koff = [Wk;Woff]@x+b  M=4096, BM=64, 4 ntiles of 128
// ---------------------------------------------------------------------------
__global__ __launch_bounds__(256, 4) void mfma_gemm(
    const float* __restrict__ y, const float* __restrict__ x,
    const float* __restrict__ Wq, const float* __restrict__ Wk,
    const float* __restrict__ Woff,
    const float* __restrict__ bq, const float* __restrict__ bk,
    const float* __restrict__ boff,
    ushort* __restrict__ qbf, ushort* __restrict__ kbf,
    float* __restrict__ offw)
{
    __shared__ __align__(16) ushort sY[64][68];
    __shared__ __align__(16) ushort sB[128][72];

    int bid = blockIdx.x;
    const float* SRC; const float* ba; const float* bb;
    ushort* OBF; float* OFP;
    int M, m0, n0, b;
    bool isQ = (bid < 512);
    if (isQ) {
        int mt = bid & 255; b = bid >> 8;
        SRC = y; ba = bq; bb = nullptr; OBF = qbf; OFP = nullptr;
        M = 16384; m0 = mt * 64; n0 = 0;
    } else {
        int r = bid - 512;
        int mt = r & 63, nt2 = (r >> 6) & 3; b = r >> 8;
        SRC = x; ba = bk; bb = boff; OBF = kbf; OFP = offw;
        M = 4096; m0 = mt * 64; n0 = nt2 * 128;
    }

    int tid = threadIdx.x;
    int lane = tid & 63;
    int wv = tid >> 6, wm = wv >> 1, wn = wv & 1;
    int il = lane & 15, g4 = lane >> 4;
    int st_m4 = tid & 15, st_c = tid >> 4;
    int st_c8 = tid & 7,  st_n = tid >> 3;

    // resolve weight row pointers once (rows fixed across K-steps)
    const float* wrowp[4];
#pragma unroll
    for (int i = 0; i < 4; ++i) {
        int n = n0 + st_n + i * 32;
        if (isQ)            wrowp[i] = Wq  + (size_t)n * KIN;
        else if (n < GE)    wrowp[i] = Wk  + (size_t)n * KIN;
        else if (n < GE + NOFF) wrowp[i] = Woff + (size_t)(n - GE) * KIN;
        else                wrowp[i] = nullptr;
    }

    f32x4 acc[2][4];
#pragma unroll
    for (int i = 0; i < 2; ++i)
#pragma unroll
        for (int j = 0; j < 4; ++j) { f32x4 z = {0.f,0.f,0.f,0.f}; acc[i][j] = z; }

    const float* src_b = SRC + (size_t)b * KIN * M;

    float4 ra[4]; short8v rb[4];
#pragma unroll
    for (int i = 0; i < 4; ++i)
        ra[i] = *(const float4*)&src_b[(size_t)(st_c + i * 16) * M + m0 + st_m4 * 4];
#pragma unroll
    for (int i = 0; i < 4; ++i) {
        short8v t = {0,0,0,0,0,0,0,0};
        if (wrowp[i]) {
            float4 a = *(const float4*)&wrowp[i][st_c8 * 8];
            float4 c = *(const float4*)&wrowp[i][st_c8 * 8 + 4];
            t[0]=(short)f2bf(a.x); t[1]=(short)f2bf(a.y); t[2]=(short)f2bf(a.z); t[3]=(short)f2bf(a.w);
            t[4]=(short)f2bf(c.x); t[5]=(short)f2bf(c.y); t[6]=(short)f2bf(c.z); t[7]=(short)f2bf(c.w);
        }
        rb[i] = t;
    }

    for (int ks = 0; ks < 4; ++ks) {
#pragma unroll
        for (int i = 0; i < 4; ++i) {
            ushort4 h;
            h.x = f2bf(ra[i].x); h.y = f2bf(ra[i].y);
            h.z = f2bf(ra[i].z); h.w = f2bf(ra[i].w);
            *(ushort4*)&sY[st_c + i * 16][st_m4 * 4] = h;
            *(short8v*)&sB[st_n + i * 32][st_c8 * 8] = rb[i];
        }
        __syncthreads();
        if (ks < 3) {
            int k0 = (ks + 1) * 64;
#pragma unroll
            for (int i = 0; i < 4; ++i)
                ra[i] = *(const float4*)&src_b[(size_t)(k0 + st_c + i * 16) * M + m0 + st_m4 * 4];
#pragma unroll
            for (int i = 0; i < 4; ++i) {
                short8v t = {0,0,0,0,0,0,0,0};
                if (wrowp[i]) {
                    float4 a = *(const float4*)&wrowp[i][k0 + st_c8 * 8];
                    float4 c = *(const float4*)&wrowp[i][k0 + st_c8 * 8 + 4];
                    t[0]=(short)f2bf(a.x); t[1]=(short)f2bf(a.y); t[2]=(short)f2bf(a.z); t[3]=(short)f2bf(a.w);
                    t[4]=(short)f2bf(c.x); t[5]=(short)f2bf(c.y); t[6]=(short)f2bf(c.z); t[7]=(short)f2bf(c.w);
                }
                rb[i] = t;
            }
        }
#pragma unroll
        for (int kc = 0; kc < 2; ++kc) {
            int kb = kc * 32 + g4 * 8;
            short8v af[2], bfr[4];
#pragma unroll
            for (int mf = 0; mf < 2; ++mf) {
                int m = wm * 32 + mf * 16 + il;
                short8v t;
#pragma unroll
                for (int j = 0; j < 8; ++j) t[j] = (short)sY[kb + j][m];
                af[mf] = t;
            }
#pragma unroll
            for (int nf = 0; nf < 4; ++nf)
                bfr[nf] = *(const short8v*)&sB[wn * 64 + nf * 16 + il][kb];
#pragma unroll
            for (int mf = 0; mf < 2; ++mf)
#pragma unroll
                for (int nf = 0; nf < 4; ++nf)
                    acc[mf][nf] = __builtin_amdgcn_mfma_f32_16x16x32_bf16(
                        af[mf], bfr[nf], acc[mf][nf], 0, 0, 0);
        }
        __syncthreads();
    }

#pragma unroll
    for (int mf = 0; mf < 2; ++mf) {
#pragma unroll
        for (int r = 0; r < 4; ++r) {
            int m = m0 + wm * 32 + mf * 16 + g4 * 4 + r;
            size_t row = (size_t)b * M + m;
#pragma unroll
            for (int nf = 0; nf < 4; ++nf) {
                int n = n0 + wn * 64 + nf * 16 + il;
                float v = acc[mf][nf][r];
                if (n < GE) {
                    OBF[row * 128 + n] = f2bf(v + ba[n]);
                } else {
                    int no = n - GE;
                    if (no < NOFF) OFP[row * 288 + no] = v + bb[no];
                }
            }
        }
    }
}

// ---------------------------------------------------------------------------
// Fused deformable attention via per-block dense MFMA GEMMs.
// r7 structure + LDS-op reduction: pair-packed x staging, sXt [64][72]
// (no zero-pad phase, K=64 O-GEMM + 2-col VALU correction for rp 64,65).
// ---------------------------------------------------------------------------
#define RROWS 6
#define RCOLS 11
#define RPX   66

__global__ __launch_bounds__(256, 4) void deform_kernel(
    const ushort* __restrict__ qbf,  // [B, 16384, 128] bf16 pixel-major
    const ushort* __restrict__ kbf,  // [B, 4096, 128] bf16 pixel-major
    const float* __restrict__ offw,  // [B, 4096, 288] fp32 pixel-major
    const float* __restrict__ x,     // [B, 256, 64, 64] channel-major (input)
    float* __restrict__ out)         // [B, 256, 128, 128]
{
    __shared__ __align__(16) ushort sXt[64][72];  // x region fp16 [ch][rp 0..65]
    __shared__ __align__(16) ushort sK[66][40];   // k region bf16
    __shared__ __align__(16) ushort sQ[64][40];   // q bf16
    __shared__ __align__(16) ushort sSW[64][72];  // P0: sOff fp32; P1+: S then W fp16
    __shared__ uint   sGt[576];                   // packed {ty,tx} fp16
    __shared__ int    sGz[576];                   // packed zi + flags
    __shared__ float  sAttn[576];                 // logits -> normalized attn
    __shared__ int    sFB[129];                   // fallback list

    int bx = blockIdx.x;
    int tw = bx & 7, th = (bx >> 3) & 31, g = (bx >> 8) & 3, b = bx >> 10;
    int tid = threadIdx.x;
    int wv_ = tid >> 6, lane = tid & 63;
    int row = lane & 15, kb8 = lane >> 4;

    const int ry0 = th * 2 - 2, rx0 = tw * 8 - 1;
    float* sOff = (float*)&sSW[0][0];             // [16][72] fp32 alias

    // ---------------- P0a: all staging (coalesced) -------------------------
    if (tid == 0) sFB[0] = 0;
    // x region -> fp16, pair-packed u32 stores
    for (int s = tid; s < 384; s += 256) {
        int gy = s % 6, ch = s / 6;
        int gyg = min(max(ry0 + gy, 0), 63);
        const float* xr = x + ((size_t)b * 256 + g * CGRP + ch) * 4096 + gyg * 64;
        float v[11];
        if (tw >= 1 && tw <= 6) {
            int a0 = rx0 - 3;                    // 16B-aligned, in-bounds
            float tmp[16];
#pragma unroll
            for (int t4 = 0; t4 < 4; ++t4) {
                float4 f = *(const float4*)&xr[a0 + t4 * 4];
                tmp[t4*4+0] = f.x; tmp[t4*4+1] = f.y; tmp[t4*4+2] = f.z; tmp[t4*4+3] = f.w;
            }
#pragma unroll
            for (int qx = 0; qx < RCOLS; ++qx) v[qx] = tmp[qx + 3];
        } else {
#pragma unroll
            for (int qx = 0; qx < RCOLS; ++qx) {
                int gxg = min(max(rx0 + qx, 0), 63);
                v[qx] = xr[gxg];
            }
        }
        ushort* dst = &sXt[ch][0];
        int c0 = gy * RCOLS;
        if (c0 & 1) {
            dst[c0] = f2h(v[0]);
#pragma unroll
            for (int j = 0; j < 5; ++j)
                *(uint*)&dst[c0 + 1 + 2*j] =
                    (uint)f2h(v[1 + 2*j]) | ((uint)f2h(v[2 + 2*j]) << 16);
        } else {
#pragma unroll
            for (int j = 0; j < 5; ++j)
                *(uint*)&dst[c0 + 2*j] =
                    (uint)f2h(v[2*j]) | ((uint)f2h(v[1 + 2*j]) << 16);
            dst[c0 + 10] = f2h(v[10]);
        }
    }
    // k region bf16
    for (int i = tid; i < 264; i += 256) {
        int rp = i >> 2, c4 = i & 3;
        int qy = rp / RCOLS, qx = rp - qy * RCOLS;
        int gy = min(max(ry0 + qy, 0), 63), gx = min(max(rx0 + qx, 0), 63);
        *(short8v*)&sK[rp][c4 * 8] =
            *(const short8v*)&kbf[((size_t)b * 4096 + gy * 64 + gx) * 128 +
                                  g * EMB + c4 * 8];
    }
    // q bf16
    {
        int px = tid >> 2, c4 = tid & 3;
        int hup = th * 4 + (px >> 4), wup = tw * 16 + (px & 15);
        *(short8v*)&sQ[px][c4 * 8] =
            *(const short8v*)&qbf[((size_t)b * 16384 + hup * 128 + wup) * 128 +
                                  g * EMB + c4 * 8];
    }
    // offsets (coalesced float4) -> sOff
    for (int i = tid; i < 288; i += 256) {
        int lr = i / 18, f4 = i - (i / 18) * 18;
        int yy = th * 2 + (lr >> 3), xx = tw * 8 + (lr & 7);
        *(float4*)&sOff[lr * 72 + f4 * 4] =
            *(const float4*)&offw[((size_t)b * 4096 + yy * 64 + xx) * 288 +
                                  g * 72 + f4 * 4];
    }
    __syncthreads();

    // ---------------- P0b: S-GEMM (to regs) + geometry ---------------------
    f32x4 sreg[5];
    {
        short8v a = *(const short8v*)&sQ[wv_ * 16 + row][kb8 * 8];
#pragma unroll
        for (int nt = 0; nt < 5; ++nt) {
            int rr = nt * 16 + row; if (rr > 65) rr = 65;   // tail clamp
            short8v bf = *(const short8v*)&sK[rr][kb8 * 8];
            f32x4 z = {0.f, 0.f, 0.f, 0.f};
            sreg[nt] = __builtin_amdgcn_mfma_f32_16x16x32_bf16(a, bf, z, 0, 0, 0);
        }
    }
    for (int item = tid; item < 576; item += 256) {
        int px = item / 9, pt = item - (item / 9) * 9;
        int lx = px & 15, ly = px >> 4;
        int hup = th * 4 + ly, wup = tw * 16 + lx;
        int lr = (ly >> 1) * 8 + (lx >> 1);
        int ij = ((hup & 1) << 1) | (wup & 1);
        float offy = sOff[lr * 72 + pt * 8 + ij];
        float offx = sOff[lr * 72 + pt * 8 + 4 + ij];
        float py  = offy + hup * 0.5f - 0.25f;
        float pxx = offx + wup * 0.5f - 0.25f;
        float y0f = floorf(py), x0f = floorf(pxx);
        float ty = py - y0f, tx = pxx - x0f;
        int y0 = (int)y0f, x0 = (int)x0f;
        int mk = 0;
        if ((unsigned)y0 < 64u && (unsigned)x0 < 64u)         mk |= 1;
        if ((unsigned)y0 < 64u && (unsigned)(x0+1) < 64u)     mk |= 2;
        if ((unsigned)(y0+1) < 64u && (unsigned)x0 < 64u)     mk |= 4;
        if ((unsigned)(y0+1) < 64u && (unsigned)(x0+1) < 64u) mk |= 8;
        int iy = y0 - ry0, ix = x0 - rx0;
        bool inreg = ((unsigned)iy <= (unsigned)(RROWS - 2)) &&
                     ((unsigned)ix <= (unsigned)(RCOLS - 2));
        int fl, zp;
        if (!mk)        { fl = 16; zp = 0; }
        else if (inreg) { fl = mk | 16; zp = iy * RCOLS + ix; }
        else            { fl = mk; zp = (y0 + 1) * 66 + (x0 + 1); }
        sGt[item] = (uint)f2h(ty) | ((uint)f2h(tx) << 16);
        sGz[item] = (zp << 5) | fl;
    }
    __syncthreads();

    // ---------------- P1: store S as fp16 (overwrites sOff) ----------------
#pragma unroll
    for (int nt = 0; nt < 5; ++nt) {
        int rp = nt * 16 + row;
        if (rp < RPX) {
#pragma unroll
            for (int r = 0; r < 4; ++r)
                sSW[wv_ * 16 + kb8 * 4 + r][rp] = f2h(sreg[nt][r]);
        }
    }
    __syncthreads();

    // ---------------- P2: attention logits ---------------------------------
    for (int item = tid; item < 576; item += 256) {
        int px = item / 9;
        uint gt = sGt[item];
        float ty = h2f((ushort)gt), tx = h2f((ushort)(gt >> 16));
        int z = sGz[item];
        int fl = z & 31;
        float a;
        if (fl & 16) {
            int zi = z >> 5;
            float w00 = (1.f - ty) * (1.f - tx), w01 = (1.f - ty) * tx;
            float w10 = ty * (1.f - tx), w11 = ty * tx;
            a  = (fl & 1) ? w00 * h2f(sSW[px][zi])             : 0.f;
            a += (fl & 2) ? w01 * h2f(sSW[px][zi + 1])         : 0.f;
            a += (fl & 4) ? w10 * h2f(sSW[px][zi + RCOLS])     : 0.f;
            a += (fl & 8) ? w11 * h2f(sSW[px][zi + RCOLS + 1]) : 0.f;
        } else {
            int t = z >> 5;
            int y0 = t / 66 - 1, x0 = t - (t / 66) * 66 - 1;
            a = 0.f;
#pragma unroll
            for (int c = 0; c < 4; ++c) if ((fl >> c) & 1) {
                int dy = c >> 1, dx = c & 1;
                float wgt = (dy ? ty : 1.f - ty) * (dx ? tx : 1.f - tx);
                const ushort* kr = &kbf[((size_t)b * 4096 + (y0 + dy) * 64 + x0 + dx) * 128 +
                                        g * EMB];
                float dot = 0.f;
                for (int e = 0; e < EMB; ++e) dot += bf2f(sQ[px][e]) * bf2f(kr[e]);
                a += wgt * dot;
            }
            int old = atomicAdd(&sFB[0], 1);
            if (old < 128) sFB[1 + old] = item;
        }
        sAttn[item] = a;
    }
    __syncthreads();

    // ---------------- P3: softmax (tid<64)  |  zero W (tid>=64) ------------
    if (tid < 64) {
        float aa[NPT];
        float mx = -1e30f;
#pragma unroll
        for (int p = 0; p < NPT; ++p) { aa[p] = sAttn[tid * 9 + p]; mx = fmaxf(mx, aa[p]); }
        float s = 0.f;
#pragma unroll
        for (int p = 0; p < NPT; ++p) { aa[p] = __expf(aa[p] - mx); s += aa[p]; }
        float inv = 1.f / s;
#pragma unroll
        for (int p = 0; p < NPT; ++p) sAttn[tid * 9 + p] = aa[p] * inv;
    } else {
        float4* p = (float4*)&sSW[0][0];
        float4 z4 = make_float4(0.f, 0.f, 0.f, 0.f);
        for (int i = tid - 64; i < 576; i += 192) p[i] = z4;
    }
    __syncthreads();

    // ---------------- P4: W-build (tid<64, serial fp16 RMW) ----------------
    if (tid < 64) {
        int px = tid;
#pragma unroll
        for (int pt = 0; pt < NPT; ++pt) {
            int item = px * 9 + pt;
            int z = sGz[item];
            int fl = z & 31;
            if (!(fl & 16)) continue;
            uint gt = sGt[item];
            float ty = h2f((ushort)gt), tx = h2f((ushort)(gt >> 16));
            float a = sAttn[item];
            int zi = z >> 5;
            ushort* c = &sSW[px][zi];
            if (fl & 1) c[0]         = f2h(h2f(c[0])         + (1.f-ty)*(1.f-tx)*a);
            if (fl & 2) c[1]         = f2h(h2f(c[1])         + (1.f-ty)*tx*a);
            if (fl & 4) c[RCOLS]     = f2h(h2f(c[RCOLS])     + ty*(1.f-tx)*a);
            if (fl & 8) c[RCOLS + 1] = f2h(h2f(c[RCOLS + 1]) + ty*tx*a);
        }
    }
    __syncthreads();

    // ---------------- P5: O-GEMM (f16 MFMA, K=64) + rp64/65 fix + store ----
    {
        half8v bfm[2][4];
#pragma unroll
        for (int kt = 0; kt < 2; ++kt)
#pragma unroll
            for (int nt = 0; nt < 4; ++nt)
                bfm[kt][nt] = *(const half8v*)&sXt[nt * 16 + row][kt * 32 + kb8 * 8];

        int px = wv_ * 16 + row;
        half8v af0 = *(const half8v*)&sSW[px][kb8 * 8];
        half8v af1 = *(const half8v*)&sSW[px][32 + kb8 * 8];

        f32x4 acc[4];
#pragma unroll
        for (int nt = 0; nt < 4; ++nt) { f32x4 z = {0.f,0.f,0.f,0.f}; acc[nt] = z; }
#pragma unroll
        for (int nt = 0; nt < 4; ++nt) {
            acc[nt] = __builtin_amdgcn_mfma_f32_16x16x32_f16(af0, bfm[0][nt], acc[nt], 0, 0, 0);
            acc[nt] = __builtin_amdgcn_mfma_f32_16x16x32_f16(af1, bfm[1][nt], acc[nt], 0, 0, 0);
        }
        // correction for K columns 64,65 (W cols 64-65 x X cols 64-65)
        float wc[4][2];
#pragma unroll
        for (int r = 0; r < 4; ++r) {
            uint u = *(uint*)&sSW[wv_ * 16 + kb8 * 4 + r][64];
            wc[r][0] = h2f((ushort)u); wc[r][1] = h2f((ushort)(u >> 16));
        }
#pragma unroll
        for (int nt = 0; nt < 4; ++nt) {
            uint u = *(uint*)&sXt[nt * 16 + row][64];
            float x0 = h2f((ushort)u), x1 = h2f((ushort)(u >> 16));
#pragma unroll
            for (int r = 0; r < 4; ++r)
                acc[nt][r] += wc[r][0] * x0 + wc[r][1] * x1;
        }
        int hup = th * 4 + wv_;
#pragma unroll
        for (int nt = 0; nt < 4; ++nt) {
            int ch = nt * 16 + row;
            float* ob = out + ((size_t)b * 256 + g * CGRP + ch) * 16384 +
                        hup * 128 + tw * 16 + kb8 * 4;
#pragma unroll
            for (int r = 0; r < 4; ++r) ob[r] = acc[nt][r];
        }
    }
    __syncthreads();

    // ---------------- P6: rare out-of-region fallback -----------------------
    int nfb = min(sFB[0], 128);
    for (int i = 0; i < nfb; ++i) {
        if (tid < 64) {
            int item = sFB[1 + i];
            int px = item / 9;
            uint gt = sGt[item];
            float ty = h2f((ushort)gt), tx = h2f((ushort)(gt >> 16));
            int z = sGz[item];
            float a = sAttn[item];
            int fl = z & 15;
            int t = z >> 5;
            int y0 = t / 66 - 1, x0 = t - (t / 66) * 66 - 1;
            const float* xg = x + ((size_t)b * 256 + g * CGRP + tid) * 4096;
            float v = 0.f;
            if (fl & 1) v += (1.f-ty)*(1.f-tx)*a * xg[y0*64 + x0];
            if (fl & 2) v += (1.f-ty)*tx*a       * xg[y0*64 + x0 + 1];
            if (fl & 4) v += ty*(1.f-tx)*a       * xg[(y0+1)*64 + x0];
            if (fl & 8) v += ty*tx*a             * xg[(y0+1)*64 + x0 + 1];
            int hup = th * 4 + (px >> 4), wup = tw * 16 + (px & 15);
            float* op = out + ((size_t)b * 256 + g * CGRP + tid) * 16384 +
                        hup * 128 + wup;
            *op += v;
        }
    }
}

// ---------------------------------------------------------------------------
extern "C" void kernel_launch(void* const* d_in, const int* in_sizes, int n_in,
                              void* d_out, int out_size, void* d_ws, size_t ws_size,
                              hipStream_t stream)
{
    const float* y    = (const float*)d_in[0];
    const float* x    = (const float*)d_in[1];
    const float* Wq   = (const float*)d_in[2];
    const float* bq   = (const float*)d_in[3];
    const float* Wk   = (const float*)d_in[4];
    const float* bk   = (const float*)d_in[5];
    const float* Woff = (const float*)d_in[6];
    const float* boff = (const float*)d_in[7];
    float* out = (float*)d_out;

    // workspace layout (~19.9 MB total)
    ushort* qbf   = (ushort*)d_ws;                            // 2*16384*128
    ushort* kbf   = qbf + (size_t)B_N * 16384 * 128;          // 2*4096*128
    float*  offw  = (float*)(kbf + (size_t)B_N * 4096 * 128); // 2*4096*288

    // both convs in one pipelined launch (weights converted in-kernel)
    mfma_gemm<<<dim3(1024), dim3(256), 0, stream>>>(
        y, x, Wq, Wk, Woff, bq, bk, boff, qbf, kbf, offw);

    // fused deformable attention
    deform_kernel<<<dim3(2048), dim3(256), 0, stream>>>(qbf, kbf, offw, x, out);
}